// Round 1
// baseline (50.028 us; speedup 1.0000x reference)
//
#include <hip/hip_runtime.h>

#define EPSILON 1e-7

constexpr int BLOCKS  = 2048;
constexpr int THREADS = 256;

// Stage 1: per-block partial sums of {s0, s1, n1}
//   c0 = p < 0.5 ? p : 1-p
//   s0 = sum of c0 where t==0, s1 = sum of c0 where t==1, n1 = count of t==1
__global__ __launch_bounds__(THREADS) void f1_partial_kernel(
    const float* __restrict__ pred,
    const int*   __restrict__ truth,
    float*       __restrict__ partial,   // [BLOCKS][3]
    int n4)                              // number of 4-element chunks
{
    float s0 = 0.0f, s1 = 0.0f;
    int   c1 = 0;

    const float4* p4 = reinterpret_cast<const float4*>(pred);
    const int4*   t4 = reinterpret_cast<const int4*>(truth);

    int idx    = blockIdx.x * blockDim.x + threadIdx.x;
    int stride = gridDim.x * blockDim.x;

    for (int i = idx; i < n4; i += stride) {
        float4 p = p4[i];
        int4   t = t4[i];
        float c;
        c = (p.x < 0.5f) ? p.x : 1.0f - p.x; if (t.x) s1 += c; else s0 += c; c1 += t.x;
        c = (p.y < 0.5f) ? p.y : 1.0f - p.y; if (t.y) s1 += c; else s0 += c; c1 += t.y;
        c = (p.z < 0.5f) ? p.z : 1.0f - p.z; if (t.z) s1 += c; else s0 += c; c1 += t.z;
        c = (p.w < 0.5f) ? p.w : 1.0f - p.w; if (t.w) s1 += c; else s0 += c; c1 += t.w;
    }

    // wave (64-lane) shuffle reduction
    #pragma unroll
    for (int off = 32; off > 0; off >>= 1) {
        s0 += __shfl_down(s0, off);
        s1 += __shfl_down(s1, off);
        c1 += __shfl_down(c1, off);
    }

    __shared__ float ls0[THREADS / 64];
    __shared__ float ls1[THREADS / 64];
    __shared__ int   lc1[THREADS / 64];

    int lane = threadIdx.x & 63;
    int wave = threadIdx.x >> 6;
    if (lane == 0) { ls0[wave] = s0; ls1[wave] = s1; lc1[wave] = c1; }
    __syncthreads();

    if (threadIdx.x == 0) {
        float t0 = 0.0f, t1 = 0.0f; int tc = 0;
        #pragma unroll
        for (int w = 0; w < THREADS / 64; ++w) { t0 += ls0[w]; t1 += ls1[w]; tc += lc1[w]; }
        partial[3 * blockIdx.x + 0] = t0;
        partial[3 * blockIdx.x + 1] = t1;
        partial[3 * blockIdx.x + 2] = (float)tc;   // per-block count < 2^24, exact in f32
    }
}

// Stage 2: reduce per-block partials, compute F1 loss scalar
__global__ __launch_bounds__(THREADS) void f1_final_kernel(
    const float* __restrict__ partial,
    float*       __restrict__ out,
    int nblocks, double n_total)
{
    double s0 = 0.0, s1 = 0.0, c1 = 0.0;
    for (int i = threadIdx.x; i < nblocks; i += blockDim.x) {
        s0 += (double)partial[3 * i + 0];
        s1 += (double)partial[3 * i + 1];
        c1 += (double)partial[3 * i + 2];
    }

    #pragma unroll
    for (int off = 32; off > 0; off >>= 1) {
        s0 += __shfl_down(s0, off);
        s1 += __shfl_down(s1, off);
        c1 += __shfl_down(c1, off);
    }

    __shared__ double ds0[THREADS / 64];
    __shared__ double ds1[THREADS / 64];
    __shared__ double dc1[THREADS / 64];

    int lane = threadIdx.x & 63;
    int wave = threadIdx.x >> 6;
    if (lane == 0) { ds0[wave] = s0; ds1[wave] = s1; dc1[wave] = c1; }
    __syncthreads();

    if (threadIdx.x == 0) {
        double S0 = 0.0, S1 = 0.0, C1 = 0.0;
        #pragma unroll
        for (int w = 0; w < THREADS / 64; ++w) { S0 += ds0[w]; S1 += ds1[w]; C1 += dc1[w]; }

        double n1 = C1, n0 = n_total - n1;
        // class 0: tp=S0, fp=S1, fn=n0-S0
        // class 1: tp=n1-S1, fp=n0-S0, fn=S1
        double tp0 = S0,      fp0 = S1,      fn0 = n0 - S0;
        double tp1 = n1 - S1, fp1 = n0 - S0, fn1 = S1;

        double p0 = tp0 / (tp0 + fp0 + EPSILON);
        double r0 = tp0 / (tp0 + fn0 + EPSILON);
        double f0 = 2.0 * p0 * r0 / (p0 + r0 + EPSILON);
        f0 = fmin(fmax(f0, (double)EPSILON), 1.0 - (double)EPSILON);

        double p1 = tp1 / (tp1 + fp1 + EPSILON);
        double r1 = tp1 / (tp1 + fn1 + EPSILON);
        double f1 = 2.0 * p1 * r1 / (p1 + r1 + EPSILON);
        f1 = fmin(fmax(f1, (double)EPSILON), 1.0 - (double)EPSILON);

        out[0] = (float)(1.0 - 0.5 * (f0 + f1));
    }
}

extern "C" void kernel_launch(void* const* d_in, const int* in_sizes, int n_in,
                              void* d_out, int out_size, void* d_ws, size_t ws_size,
                              hipStream_t stream) {
    const float* pred  = (const float*)d_in[0];
    const int*   truth = (const int*)d_in[1];
    float*       out   = (float*)d_out;
    float*       partial = (float*)d_ws;   // BLOCKS*3 floats = 24 KiB

    int n  = in_sizes[0];
    int n4 = n / 4;                        // N = 2^25, divisible by 4

    f1_partial_kernel<<<BLOCKS, THREADS, 0, stream>>>(pred, truth, partial, n4);
    f1_final_kernel<<<1, THREADS, 0, stream>>>(partial, out, BLOCKS, (double)n);
}